// Round 4
// baseline (7106.038 us; speedup 1.0000x reference)
//
#include <hip/hip_runtime.h>
#include <hip/hip_bf16.h>

typedef unsigned short u16;
typedef unsigned int u32;

// RowLSTM  B=32, Cin=3, H=W=64, HC=128, gates 4*HC=512 (order o,f,i,g)
// Masked 'B' 1x3 conv => 2 taps: y[w] = sum_ic v[w-1]*W[...,0] + v[w]*W[...,1]
// ALL I/O fp32 (per reference). ONE persistent kernel, 256 blocks =
// (hct in [0,8), b in [0,32)); block owns hc slice [16*hct,16*hct+16), all 4 gates.
// c-state in registers; h exchanged through `out` rows (fp32), per-b lock-free
// barrier (8 blocks/group) with device-scope fences.

__device__ __forceinline__ float b2f(u16 u) {
    u32 v = ((u32)u) << 16; return __builtin_bit_cast(float, v);
}
__device__ __forceinline__ u16 f2b(float f) {
    return __builtin_bit_cast(u16, __float2bfloat16(f));
}
__device__ __forceinline__ float sigm(float x) { return 1.0f / (1.0f + __expf(-x)); }
__device__ __forceinline__ float tanh_fast(float x) {
    return 1.0f - 2.0f / (__expf(2.0f * x) + 1.0f);   // exact saturation at +-inf
}

__global__ __launch_bounds__(512, 1) void rowlstm_persistent(
    const float* __restrict__ x,   const float* __restrict__ Wis,
    const float* __restrict__ bis, const float* __restrict__ Wss,
    const float* __restrict__ bss, const float* __restrict__ h0,
    const float* __restrict__ c0,  float* out, int* bar)
{
    // LDS: 32768 + 18432 + 864 + 1536 + 256 = 53,856 B
    __shared__ __align__(16) u16  lds_w[16384];    // [ic][hcl][g][tap] bf16
    __shared__ __align__(16) u16  lds_h[128 * 72]; // [ic][p]; h[w] at p=w+8, h[-1] at p=7
    __shared__ float lds_x [3 * 72];               // [cch][p]; x[w] at p=w+8, x[-1] at p=7
    __shared__ float lds_wx[384];                  // [cch][hcl][g][tap]
    __shared__ float lds_b [64];                   // [hcl][g] = b_is + b_ss

    const int tid = threadIdx.x;
    const int hct = blockIdx.x;      // [0,8)
    const int b   = blockIdx.y;      // [0,32)
    int* bar_b = bar + b * 16;       // 64 B spacing between group counters

    // ---------- one-time staging (weights fixed across all 64 rows) ----------
    #pragma unroll
    for (int s = 0; s < 32; ++s) {
        int idx = tid + s * 512;                   // [ic][hcl][g][tap]
        int tap = idx & 1, g = (idx >> 1) & 3, hcl = (idx >> 3) & 15, ic = idx >> 7;
        int oc = g * 128 + hct * 16 + hcl;
        lds_w[idx] = f2b(Wss[(oc * 128 + ic) * 3 + tap]);
    }
    if (tid < 384) {
        int tap = tid & 1, g = (tid >> 1) & 3, hcl = (tid >> 3) & 15, cch = tid >> 7;
        int oc = g * 128 + hct * 16 + hcl;
        lds_wx[cch * 128 + hcl * 8 + g * 2 + tap] = Wis[(oc * 3 + cch) * 3 + tap];
    }
    if (tid < 64) {
        int g = tid & 3, hcl = tid >> 2;
        int oc = g * 128 + hct * 16 + hcl;
        lds_b[hcl * 4 + g] = bis[oc] + bss[oc];
    }
    if (tid < 128) {                               // zero pad slots p=0..7 (holds h[-1]=0)
        uint4 z = make_uint4(0, 0, 0, 0);
        *(uint4*)&lds_h[tid * 72] = z;             // byte 144*tid, 16B aligned
    }
    if (tid < 3) lds_x[tid * 72 + 7] = 0.0f;       // x[-1] = 0

    const int hcl = tid & 15;                      // hc within slice
    const int wg  = tid >> 4;                      // [0,32): w = 2*wg + j

    // c-state in registers (fp32, persists across rows)
    float c[2];
    {
        int hc = hct * 16 + hcl;
        c[0] = c0[hc * 64 + 2 * wg + 0];
        c[1] = c0[hc * 64 + 2 * wg + 1];
    }

    for (int r = 0; r < 64; ++r) {
        // ---- barrier: wait for all 8 peer blocks to publish row r-1 ----
        if (r > 0) {
            if (tid == 0) {
                int target = 8 * r;
                while (__hip_atomic_load(bar_b, __ATOMIC_ACQUIRE, __HIP_MEMORY_SCOPE_AGENT) < target)
                    __builtin_amdgcn_s_sleep(1);
            }
            __syncthreads();
            __threadfence();                       // acquire at device scope (cross-XCD)
        }

        // ---- stage h_prev into LDS (full 128 ic x 64 w coverage: 2048 float4 chunks) ----
        #pragma unroll
        for (int it = 0; it < 4; ++it) {
            int chunk = tid + it * 512;            // 0..2047
            int ic = chunk >> 4, ch = chunk & 15;  // 16 chunks of 4 floats per ic row
            float4 hv;
            if (r == 0) hv = *(const float4*)(h0 + ic * 64 + ch * 4);   // broadcast over b
            else        hv = *(const float4*)(out + ((size_t)(b * 128 + ic) * 64 + (r - 1)) * 64 + ch * 4);
            u32 lo = (u32)f2b(hv.x) | ((u32)f2b(hv.y) << 16);
            u32 hi = (u32)f2b(hv.z) | ((u32)f2b(hv.w) << 16);
            *(uint2*)&lds_h[ic * 72 + 8 + ch * 4] = make_uint2(lo, hi);  // 8B aligned
        }
        if (tid < 192) {                           // stage x row (fp32)
            int cch = tid >> 6, w = tid & 63;
            lds_x[cch * 72 + 8 + w] = x[((size_t)(b * 3 + cch) * 64 + r) * 64 + w];
        }
        __syncthreads();

        // ---- gates: bias + x-conv + h-conv ----
        float acc[4][2];
        #pragma unroll
        for (int g = 0; g < 4; ++g) {
            float bv = lds_b[hcl * 4 + g];
            acc[g][0] = bv; acc[g][1] = bv;
        }
        #pragma unroll
        for (int cch = 0; cch < 3; ++cch) {
            float xv0 = lds_x[cch * 72 + 2 * wg + 7];
            float xv1 = lds_x[cch * 72 + 2 * wg + 8];
            float xv2 = lds_x[cch * 72 + 2 * wg + 9];
            #pragma unroll
            for (int g = 0; g < 4; ++g) {
                float w0 = lds_wx[cch * 128 + hcl * 8 + g * 2 + 0];
                float w1 = lds_wx[cch * 128 + hcl * 8 + g * 2 + 1];
                acc[g][0] += w0 * xv0 + w1 * xv1;
                acc[g][1] += w0 * xv1 + w1 * xv2;
            }
        }
        #pragma unroll 4
        for (int ic = 0; ic < 128; ++ic) {
            float hv0 = b2f(lds_h[ic * 72 + 2 * wg + 7]);   // h[2wg-1]
            float hv1 = b2f(lds_h[ic * 72 + 2 * wg + 8]);   // h[2wg]
            float hv2 = b2f(lds_h[ic * 72 + 2 * wg + 9]);   // h[2wg+1]
            const u16* wp = &lds_w[ic * 128 + hcl * 8];      // 8 contiguous bf16 (16B aligned)
            #pragma unroll
            for (int g = 0; g < 4; ++g) {
                float w0 = b2f(wp[g * 2 + 0]);
                float w1 = b2f(wp[g * 2 + 1]);
                acc[g][0] = __builtin_fmaf(w0, hv0, __builtin_fmaf(w1, hv1, acc[g][0]));
                acc[g][1] = __builtin_fmaf(w0, hv1, __builtin_fmaf(w1, hv2, acc[g][1]));
            }
        }

        // ---- LSTM cell (registers) -> write h row (fp32) ----
        float2 hv2;
        {
            float o  = sigm(acc[0][0]);
            float f  = sigm(acc[1][0]);
            float ii = sigm(acc[2][0]);
            float gg = sigm(acc[3][0]);
            c[0] = f * c[0] + ii * gg;
            hv2.x = o * tanh_fast(c[0]);
        }
        {
            float o  = sigm(acc[0][1]);
            float f  = sigm(acc[1][1]);
            float ii = sigm(acc[2][1]);
            float gg = sigm(acc[3][1]);
            c[1] = f * c[1] + ii * gg;
            hv2.y = o * tanh_fast(c[1]);
        }
        {
            int hc = hct * 16 + hcl;
            *(float2*)(out + ((size_t)(b * 128 + hc) * 64 + r) * 64 + 2 * wg) = hv2;
        }

        // ---- publish row r ----
        __threadfence();                           // release: drain stores to device scope
        __syncthreads();                           // all threads' stores fenced
        if (tid == 0)
            __hip_atomic_fetch_add(bar_b, 1, __ATOMIC_RELEASE, __HIP_MEMORY_SCOPE_AGENT);
    }
}

extern "C" void kernel_launch(void* const* d_in, const int* in_sizes, int n_in,
                              void* d_out, int out_size, void* d_ws, size_t ws_size,
                              hipStream_t stream)
{
    const float* x   = (const float*)d_in[0];
    const float* Wis = (const float*)d_in[1];
    const float* bis = (const float*)d_in[2];
    const float* Wss = (const float*)d_in[3];
    const float* bss = (const float*)d_in[4];
    const float* h0  = (const float*)d_in[5];
    const float* c0  = (const float*)d_in[6];
    float* out = (float*)d_out;
    int* bar = (int*)d_ws;

    // zero the 32 per-b barrier counters (capture-legal async memset)
    hipMemsetAsync(d_ws, 0, 4096, stream);

    rowlstm_persistent<<<dim3(8, 32), 512, 0, stream>>>(
        x, Wis, bis, Wss, bss, h0, c0, out, bar);
}

// Round 5
// 473.282 us; speedup vs baseline: 15.0144x; 15.0144x over previous
//
#include <hip/hip_runtime.h>
#include <hip/hip_bf16.h>

typedef unsigned short u16;
typedef unsigned int u32;
typedef short bf16x8 __attribute__((ext_vector_type(8)));   // 8 bf16 (4 VGPRs)
typedef float f32x4  __attribute__((ext_vector_type(4)));   // MFMA C/D

// RowLSTM B=32, Cin=3, H=W=64, HC=128, gates 4*HC (order o,f,i,g).
// Masked-B 1x3 conv => 2 taps (w-1, w). One block per batch: the whole h
// recurrence is block-local (LDS), NO cross-block sync/fences (round-4's
// agent-scope fence storm was 91% of runtime: 111us/row vs ~10us compute).
//
// GEMM per row: gates[512 oc][64 w] = A[512][288] * B[288][64] via
// mfma_f32_16x16x32_bf16.  K = 8 h-tiles (ic x tap) + 1 x-tile (cch x tap).
// Wave wid owns m-tiles {g*8+wid, g=0..3} -> oc = g*128 + wid*16 + (q*4+reg)
// so o,f,i,g of one hc share lane+reg across the 4 accs: cell is in-register.
// A-frags (weights) persist in VGPRs (36 frags = 144 VGPR); c-state in 16 VGPR.
// B-layout LDS: frag tile (kt,nt) = 64 lanes x 16B contiguous (ds_read_b128).

__device__ __forceinline__ u16 f2b(float f) {
    return __builtin_bit_cast(u16, __float2bfloat16(f));
}
__device__ __forceinline__ float sigm(float x) {
    return __builtin_amdgcn_rcpf(1.0f + __expf(-x));
}
__device__ __forceinline__ float tanh_fast(float x) {
    // 1 - 2/(exp(2x)+1): exact saturation at +-inf
    return 1.0f - 2.0f * __builtin_amdgcn_rcpf(__expf(2.0f * x) + 1.0f);
}

__global__ __launch_bounds__(512, 2) void rowlstm_mfma(
    const float* __restrict__ x,   const float* __restrict__ Wis,
    const float* __restrict__ bis, const float* __restrict__ Wss,
    const float* __restrict__ bss, const float* __restrict__ h0,
    const float* __restrict__ c0,  float* __restrict__ out)
{
    __shared__ __align__(16) char lds_B[36 * 1024];  // 9 kt x 4 nt x 64 lanes x 16B
    __shared__ float lds_bias[512];

    const int tid  = threadIdx.x;
    const int b    = blockIdx.x;        // batch
    const int wid  = tid >> 6;          // wave [0,8)
    const int lane = tid & 63;
    const int q    = (tid >> 4) & 3;    // quad within wave
    const int n    = tid & 15;          // A: m-index; B/D: n-index (w within tile)

    // ---- bias (b_is + b_ss) ----
    lds_bias[tid] = bis[tid] + bss[tid];

    // ---- zero constant B slots ----
    // (a) tap0 w_out=0 slots (kt<8, nt=0, n=0, all q, j even): never scattered
    if (tid < 128) {
        int kt = tid >> 4, qq = (tid >> 2) & 3, jj = tid & 3;
        *(u16*)(lds_B + (((kt * 4 + 0) * 64 + qq * 16 + 0) * 16) + (2 * jj) * 2) = 0;
    }
    // (b) x-tile (kt=8) q>0 slots: k>=8 rows of the x K-tile are always zero
    if (tid < 256 && (tid & 63) >= 16) {
        int nt = tid >> 6, ln = tid & 63;
        *(uint4*)(lds_B + ((32 + nt) * 64 + ln) * 16) = make_uint4(0, 0, 0, 0);
    }

    // ---- A-fragments (weights, bf16) -> registers, persist across all rows ----
    // A[m=lane&15][k=q*8+j]; k even = tap0 (w-1), k odd = tap1 (w).
    bf16x8 afr[4][9];
    {
        const int m = n;
        #pragma unroll
        for (int g = 0; g < 4; ++g) {
            int oc = g * 128 + wid * 16 + m;
            #pragma unroll
            for (int kt = 0; kt < 8; ++kt) {
                bf16x8 a;
                #pragma unroll
                for (int jj = 0; jj < 4; ++jj) {
                    int ic = kt * 16 + q * 4 + jj;
                    float2 wp = *(const float2*)&Wss[(size_t)(oc * 128 + ic) * 3];
                    a[2 * jj]     = (short)f2b(wp.x);   // tap0
                    a[2 * jj + 1] = (short)f2b(wp.y);   // tap1
                }
                afr[g][kt] = a;
            }
            // kt=8: input-conv weights (3 cch x 2 taps), only k<6 (q==0) nonzero
            bf16x8 ax = {0, 0, 0, 0, 0, 0, 0, 0};
            if (q == 0) {
                #pragma unroll
                for (int cch = 0; cch < 3; ++cch) {
                    float2 wp = *(const float2*)&Wis[(size_t)(oc * 3 + cch) * 3];
                    ax[2 * cch]     = (short)f2b(wp.x);
                    ax[2 * cch + 1] = (short)f2b(wp.y);
                }
            }
            afr[g][8] = ax;
        }
    }

    // ---- c-state + initial h (registers) ----
    float cst[16];
    u16 hv[4][4];
    #pragma unroll
    for (int nt = 0; nt < 4; ++nt)
        #pragma unroll
        for (int reg = 0; reg < 4; ++reg) {
            int hc = wid * 16 + q * 4 + reg;
            int w  = nt * 16 + n;
            cst[nt * 4 + reg] = c0[hc * 64 + w];        // broadcast over b
            hv[nt][reg] = f2b(h0[hc * 64 + w]);
        }

    // ---- scatter h into B-layout (both taps). kt = wid for this wave's hc. ----
    auto scatter_h = [&]() {
        #pragma unroll
        for (int nt = 0; nt < 4; ++nt) {
            int base1 = ((wid * 4 + nt) * 64 + lane) * 16;
            #pragma unroll
            for (int reg = 0; reg < 4; ++reg) {
                // tap1 (k = 8q+2reg+1): same w
                *(u16*)(lds_B + base1 + (2 * reg + 1) * 2) = hv[nt][reg];
                // tap0 (k = 8q+2reg): contributes to w+1
                int wo = nt * 16 + n + 1;
                if (wo < 64)
                    *(u16*)(lds_B + (((wid * 4 + (wo >> 4)) * 64 + q * 16 + (wo & 15)) * 16)
                            + (2 * reg) * 2) = hv[nt][reg];
            }
        }
    };
    // ---- build x K-tile (kt=8) for row r1: q==0 slots only ----
    auto build_x = [&](int r1) {
        if (tid < 64) {
            int nt = tid >> 4, nn = tid & 15, w = nt * 16 + nn;
            u32 wd[3];
            #pragma unroll
            for (int cch = 0; cch < 3; ++cch) {
                const float* xr = x + ((size_t)(b * 3 + cch) * 64 + r1) * 64;
                u16 e0 = (w >= 1) ? f2b(xr[w - 1]) : (u16)0;  // tap0
                u16 e1 = f2b(xr[w]);                           // tap1
                wd[cch] = (u32)e0 | ((u32)e1 << 16);
            }
            *(uint4*)(lds_B + ((32 + nt) * 64 + nn) * 16) = make_uint4(wd[0], wd[1], wd[2], 0);
        }
    };

    scatter_h();        // h0 (all prologue LDS writes are to disjoint slots)
    build_x(0);
    __syncthreads();

    // ================= row loop =================
    for (int r = 0; r < 64; ++r) {
        #pragma unroll
        for (int nt = 0; nt < 4; ++nt) {
            f32x4 acc[4];
            #pragma unroll
            for (int g = 0; g < 4; ++g) {
                int oc = g * 128 + wid * 16 + q * 4;
                acc[g][0] = lds_bias[oc + 0];
                acc[g][1] = lds_bias[oc + 1];
                acc[g][2] = lds_bias[oc + 2];
                acc[g][3] = lds_bias[oc + 3];
            }
            #pragma unroll
            for (int kt = 0; kt < 9; ++kt) {
                bf16x8 bf = *(const bf16x8*)(lds_B + ((kt * 4 + nt) * 64 + lane) * 16);
                acc[0] = __builtin_amdgcn_mfma_f32_16x16x32_bf16(afr[0][kt], bf, acc[0], 0, 0, 0);
                acc[1] = __builtin_amdgcn_mfma_f32_16x16x32_bf16(afr[1][kt], bf, acc[1], 0, 0, 0);
                acc[2] = __builtin_amdgcn_mfma_f32_16x16x32_bf16(afr[2][kt], bf, acc[2], 0, 0, 0);
                acc[3] = __builtin_amdgcn_mfma_f32_16x16x32_bf16(afr[3][kt], bf, acc[3], 0, 0, 0);
            }
            // D layout: col=lane&15 (=w), row=q*4+reg (=oc within tile)
            #pragma unroll
            for (int reg = 0; reg < 4; ++reg) {
                float o  = sigm(acc[0][reg]);
                float f  = sigm(acc[1][reg]);
                float ii = sigm(acc[2][reg]);
                float gg = sigm(acc[3][reg]);
                float cn = f * cst[nt * 4 + reg] + ii * gg;
                cst[nt * 4 + reg] = cn;
                float h = o * tanh_fast(cn);
                int hc = wid * 16 + q * 4 + reg;
                out[(((size_t)(b * 128 + hc)) * 64 + r) * 64 + nt * 16 + n] = h;
                hv[nt][reg] = f2b(h);
            }
        }
        __syncthreads();        // all waves done reading B for row r
        scatter_h();            // publish h[r] as next row's B
        if (r < 63) build_x(r + 1);
        __syncthreads();        // B complete before row r+1 MFMA
    }
}

extern "C" void kernel_launch(void* const* d_in, const int* in_sizes, int n_in,
                              void* d_out, int out_size, void* d_ws, size_t ws_size,
                              hipStream_t stream)
{
    const float* x   = (const float*)d_in[0];
    const float* Wis = (const float*)d_in[1];
    const float* bis = (const float*)d_in[2];
    const float* Wss = (const float*)d_in[3];
    const float* bss = (const float*)d_in[4];
    const float* h0  = (const float*)d_in[5];
    const float* c0  = (const float*)d_in[6];
    float* out = (float*)d_out;

    rowlstm_mfma<<<dim3(32), 512, 0, stream>>>(x, Wis, bis, Wss, bss, h0, c0, out);
}

// Round 6
// 287.481 us; speedup vs baseline: 24.7183x; 1.6463x over previous
//
#include <hip/hip_runtime.h>
#include <hip/hip_bf16.h>

typedef unsigned short u16;
typedef unsigned int u32;
typedef unsigned long long u64;
typedef short bf16x8 __attribute__((ext_vector_type(8)));
typedef float f32x4  __attribute__((ext_vector_type(4)));

// RowLSTM B=32, Cin=3, H=W=64, HC=128, gates o,f,i,g (all sigmoid), c=f*c+i*g,
// h=o*tanh(c). Masked-B 1x3 conv: taps (w-1, w).
//
// Round 6: 64 blocks = (s in {0,1} w-half, b in [0,32)). Per block: GEMM
// gates[512][32] via mfma_f32_16x16x32_bf16, h recirculates in LDS.
// K-tile map: k=q*8+j, j<4 -> tap1 of ic=kt*16+q*4+j, j>=4 -> tap0 (same ic).
// => a thread's 4 h values = one u64, written as d0d1 of its own B-line and
// d2d3 of lane+1's line (aligned ds_write_b64, no sub-dword scatter).
// Double-buffered B region -> ONE barrier per row.
// Cross-block: only h[:,31] b0->b1, via RELAXED agent-scope atomics (cache-
// bypassing, no acquire/release fences -> no buffer_inv/wbl2 storms).
// Per-row halo slots + per-wave monotone flags; ordering by s_waitcnt vmcnt(0).

__device__ __forceinline__ u16 f2b(float f) {
    return __builtin_bit_cast(u16, __float2bfloat16(f));
}
__device__ __forceinline__ float sigm(float x) {
    return __builtin_amdgcn_rcpf(1.0f + __expf(-x));
}
__device__ __forceinline__ float tanh_fast(float x) {
    return 1.0f - 2.0f * __builtin_amdgcn_rcpf(__expf(2.0f * x) + 1.0f);
}

#define LINE(kt, nt, lane) ((((kt) * 2 + (nt)) * 64 + (lane)) * 16)
#define BUFBYTES (9 * 2 * 64 * 16)   /* 18432 B per buffer */

__global__ __launch_bounds__(512, 2) void rowlstm_mfma2(
    const float* __restrict__ x,   const float* __restrict__ Wis,
    const float* __restrict__ bis, const float* __restrict__ Wss,
    const float* __restrict__ bss, const float* __restrict__ h0,
    const float* __restrict__ c0,  float* __restrict__ out,
    u32* flags, char* halo)
{
    __shared__ __align__(16) char lds_buf[2 * BUFBYTES];   // 36864 B
    __shared__ u16  lds_x[3 * 64 * 33];                     // 12672 B
    __shared__ float lds_bias[512];                         // 2048 B

    const int tid  = threadIdx.x;
    const int s    = blockIdx.x;            // w-half
    const int b    = blockIdx.y;            // batch
    const int wid  = tid >> 6;              // wave [0,8) = hc-tile
    const int lane = tid & 63;
    const int q    = lane >> 4;             // quad
    const int n    = lane & 15;             // n-index (w within 16-tile)
    const int wbase = s * 32;

    u32* flg = flags + b * 16;                         // 8 per-wave flags used
    char* hslots = halo + (size_t)b * 64 * 256;        // per-row 256 B slots

    // ---------- phase 0: zero both B buffers ----------
    #pragma unroll
    for (int i = tid; i < 2304; i += 512)
        *(uint4*)(lds_buf + i * 16) = make_uint4(0, 0, 0, 0);
    __syncthreads();

    // ---------- phase 1: one-time staging ----------
    lds_bias[tid] = bis[tid] + bss[tid];

    // x -> LDS bf16: [cch][r][wl1], wl1 = local w + 1 (col 0 = left halo / 0)
    for (int i = tid; i < 6336; i += 512) {
        int cch = i / 2112, rem = i % 2112;
        int r = rem / 33, wl1 = rem % 33;
        int gw = wbase + wl1 - 1;
        lds_x[i] = (gw < 0) ? (u16)0
                 : f2b(x[(((size_t)b * 3 + cch) * 64 + r) * 64 + gw]);
    }

    // A-fragments (persist in regs): a[j]=tap1(ic=kt*16+q*4+j), a[4+j]=tap0
    bf16x8 afr[4][9];
    {
        #pragma unroll
        for (int g = 0; g < 4; ++g) {
            int oc = g * 128 + wid * 16 + n;           // m = n
            #pragma unroll
            for (int kt = 0; kt < 8; ++kt) {
                bf16x8 a;
                #pragma unroll
                for (int jj = 0; jj < 4; ++jj) {
                    int ic = kt * 16 + q * 4 + jj;
                    float2 wp = *(const float2*)&Wss[(size_t)(oc * 128 + ic) * 3];
                    a[jj]     = (short)f2b(wp.y);      // tap1 (center)
                    a[4 + jj] = (short)f2b(wp.x);      // tap0 (left)
                }
                afr[g][kt] = a;
            }
            bf16x8 ax = {0, 0, 0, 0, 0, 0, 0, 0};
            if (q == 0) {
                #pragma unroll
                for (int cch = 0; cch < 3; ++cch) {
                    float2 wp = *(const float2*)&Wis[(size_t)(oc * 3 + cch) * 3];
                    ax[cch]     = (short)f2b(wp.y);
                    ax[4 + cch] = (short)f2b(wp.x);
                }
            }
            afr[g][8] = ax;
        }
    }

    // c-state (fp32, registers) + h0 publish into buf0
    float cst[8];
    #pragma unroll
    for (int nt = 0; nt < 2; ++nt) {
        u16 hw[4];
        #pragma unroll
        for (int reg = 0; reg < 4; ++reg) {
            int hc = wid * 16 + q * 4 + reg;
            int wg = wbase + nt * 16 + n;
            cst[nt * 4 + reg] = c0[hc * 64 + wg];
            hw[reg] = f2b(h0[hc * 64 + wg]);
        }
        u64 d01 = (u64)((u32)hw[0] | ((u32)hw[1] << 16))
                | ((u64)((u32)hw[2] | ((u32)hw[3] << 16)) << 32);
        *(u64*)(lds_buf + LINE(wid, nt, lane)) = d01;          // tap1 halves
        int wl = nt * 16 + n + 1;
        if (wl < 32)
            *(u64*)(lds_buf + LINE(wid, wl >> 4, q * 16 + (wl & 15)) + 8) = d01;
    }
    // block1: w_local=0 tap0 column from h0[:,31]
    if (s == 1 && tid < 32) {
        int ic0 = tid * 4;
        u64 v = (u64)((u32)f2b(h0[(ic0 + 0) * 64 + 31]) | ((u32)f2b(h0[(ic0 + 1) * 64 + 31]) << 16))
              | ((u64)((u32)f2b(h0[(ic0 + 2) * 64 + 31]) | ((u32)f2b(h0[(ic0 + 3) * 64 + 31]) << 16)) << 32);
        *(u64*)(lds_buf + LINE(tid >> 2, 0, (tid & 3) * 16) + 8) = v;
    }
    // x K-tile for row 0 into buf0 (q==0 lines only; q>0 lines stay zero)
    if (tid < 32) {
        int nt = tid >> 4, nn = tid & 15, wl = nt * 16 + nn;
        const u16* xb = lds_x;
        u32 d0 = (u32)xb[(0 * 64 + 0) * 33 + wl + 1] | ((u32)xb[(1 * 64 + 0) * 33 + wl + 1] << 16);
        u32 d1 = (u32)xb[(2 * 64 + 0) * 33 + wl + 1];
        u32 d2 = (u32)xb[(0 * 64 + 0) * 33 + wl]     | ((u32)xb[(1 * 64 + 0) * 33 + wl] << 16);
        u32 d3 = (u32)xb[(2 * 64 + 0) * 33 + wl];
        *(uint4*)(lds_buf + LINE(8, nt, nn)) = make_uint4(d0, d1, d2, d3);
    }
    __syncthreads();

    // ================= row loop: ONE barrier per row =================
    for (int r = 0; r < 64; ++r) {
        char* rbuf = lds_buf + (r & 1) * BUFBYTES;
        char* wbuf = lds_buf + ((r & 1) ^ 1) * BUFBYTES;

        #pragma unroll
        for (int nt = 0; nt < 2; ++nt) {
            f32x4 acc[4];
            #pragma unroll
            for (int g = 0; g < 4; ++g) {
                int oc = g * 128 + wid * 16 + q * 4;
                acc[g][0] = lds_bias[oc + 0];
                acc[g][1] = lds_bias[oc + 1];
                acc[g][2] = lds_bias[oc + 2];
                acc[g][3] = lds_bias[oc + 3];
            }
            #pragma unroll
            for (int kt = 0; kt < 9; ++kt) {
                bf16x8 bv = *(const bf16x8*)(rbuf + LINE(kt, nt, lane));
                acc[0] = __builtin_amdgcn_mfma_f32_16x16x32_bf16(afr[0][kt], bv, acc[0], 0, 0, 0);
                acc[1] = __builtin_amdgcn_mfma_f32_16x16x32_bf16(afr[1][kt], bv, acc[1], 0, 0, 0);
                acc[2] = __builtin_amdgcn_mfma_f32_16x16x32_bf16(afr[2][kt], bv, acc[2], 0, 0, 0);
                acc[3] = __builtin_amdgcn_mfma_f32_16x16x32_bf16(afr[3][kt], bv, acc[3], 0, 0, 0);
            }
            // D: col = n (w), row = q*4+reg (oc in tile)
            u16 hw[4];
            #pragma unroll
            for (int reg = 0; reg < 4; ++reg) {
                float o  = sigm(acc[0][reg]);
                float f  = sigm(acc[1][reg]);
                float ii = sigm(acc[2][reg]);
                float gg = sigm(acc[3][reg]);
                float cn = f * cst[nt * 4 + reg] + ii * gg;
                cst[nt * 4 + reg] = cn;
                float h = o * tanh_fast(cn);
                int hc = wid * 16 + q * 4 + reg;
                out[(((size_t)(b * 128 + hc)) * 64 + r) * 64 + wbase + nt * 16 + n] = h;
                hw[reg] = f2b(h);
            }
            u64 d01 = (u64)((u32)hw[0] | ((u32)hw[1] << 16))
                    | ((u64)((u32)hw[2] | ((u32)hw[3] << 16)) << 32);
            *(u64*)(wbuf + LINE(wid, nt, lane)) = d01;         // tap1 halves
            int wl = nt * 16 + n + 1;
            if (wl < 32)
                *(u64*)(wbuf + LINE(wid, wl >> 4, q * 16 + (wl & 15)) + 8) = d01;
            else if (s == 0 && r < 63)                          // halo h[:,31] -> b1
                __hip_atomic_store((u64*)(hslots + (size_t)r * 256 + (wid * 4 + q) * 8),
                                   d01, __ATOMIC_RELAXED, __HIP_MEMORY_SCOPE_AGENT);
        }
        // publish flag: this wave's halo store has drained (per-wave vmcnt)
        if (s == 0 && lane == 15 && r < 63) {
            asm volatile("s_waitcnt vmcnt(0)" ::: "memory");
            __hip_atomic_store(&flg[wid], (u32)(r + 1),
                               __ATOMIC_RELAXED, __HIP_MEMORY_SCOPE_AGENT);
        }
        if (r < 63) {
            // x K-tile for row r+1
            if (tid < 32) {
                int nt = tid >> 4, nn = tid & 15, wl = nt * 16 + nn;
                int r1 = r + 1;
                u32 d0 = (u32)lds_x[(0 * 64 + r1) * 33 + wl + 1] | ((u32)lds_x[(1 * 64 + r1) * 33 + wl + 1] << 16);
                u32 d1 = (u32)lds_x[(2 * 64 + r1) * 33 + wl + 1];
                u32 d2 = (u32)lds_x[(0 * 64 + r1) * 33 + wl]     | ((u32)lds_x[(1 * 64 + r1) * 33 + wl] << 16);
                u32 d3 = (u32)lds_x[(2 * 64 + r1) * 33 + wl];
                *(uint4*)(wbuf + LINE(8, nt, nn)) = make_uint4(d0, d1, d2, d3);
            }
            // b1: receive halo h[:,31] of row r -> w_local=0 tap0 column
            if (s == 1 && tid < 32) {
                while (__hip_atomic_load(&flg[tid >> 2], __ATOMIC_RELAXED,
                                         __HIP_MEMORY_SCOPE_AGENT) <= (u32)r)
                    __builtin_amdgcn_s_sleep(2);
                u64 v = __hip_atomic_load((u64*)(hslots + (size_t)r * 256 + tid * 8),
                                          __ATOMIC_RELAXED, __HIP_MEMORY_SCOPE_AGENT);
                *(u64*)(wbuf + LINE(tid >> 2, 0, (tid & 3) * 16) + 8) = v;
            }
        }
        __syncthreads();
    }
}

extern "C" void kernel_launch(void* const* d_in, const int* in_sizes, int n_in,
                              void* d_out, int out_size, void* d_ws, size_t ws_size,
                              hipStream_t stream)
{
    const float* x   = (const float*)d_in[0];
    const float* Wis = (const float*)d_in[1];
    const float* bis = (const float*)d_in[2];
    const float* Wss = (const float*)d_in[3];
    const float* bss = (const float*)d_in[4];
    const float* h0  = (const float*)d_in[5];
    const float* c0  = (const float*)d_in[6];
    float* out = (float*)d_out;

    // flags: 32 batches x 16 u32 (2048 B); halo slots at +4096 (32*64*256 B)
    hipMemsetAsync(d_ws, 0, 4096, stream);
    rowlstm_mfma2<<<dim3(2, 32), 512, 0, stream>>>(
        x, Wis, bis, Wss, bss, h0, c0, out,
        (u32*)d_ws, (char*)d_ws + 4096);
}

// Round 7
// 271.118 us; speedup vs baseline: 26.2102x; 1.0604x over previous
//
#include <hip/hip_runtime.h>
#include <hip/hip_bf16.h>

typedef unsigned short u16;
typedef unsigned int u32;
typedef unsigned long long u64;
typedef short bf16x8 __attribute__((ext_vector_type(8)));
typedef float f32x4  __attribute__((ext_vector_type(4)));

// RowLSTM B=32, Cin=3, H=W=64, HC=128, gates o,f,i,g (all sigmoid), c=f*c+i*g,
// h=o*tanh(c). Masked-B 1x3 conv: taps (w-1, w).
//
// Round 7: 128 blocks = (s in [0,4) w-quarter, b in [0,32)). Block: GEMM
// gates[512][16] via mfma_f32_16x16x32_bf16; h recirculates in LDS.
// K map within tile kt: k=q*8+j, j<4 -> tap1 of ic=kt*16+q*4+j, j>=4 -> tap0.
// One barrier/row (double-buffered B). Cross-block: h[:, right edge] s->s+1
// via RELAXED agent-scope atomics + per-wave monotone flags (ordering by
// in-wave s_waitcnt vmcnt(0)); pipeline offset is constant, not per-row
// (verified round 6: dur variance ~2%).

__device__ __forceinline__ u16 f2b(float f) {
    return __builtin_bit_cast(u16, __float2bfloat16(f));
}
__device__ __forceinline__ float sigm(float x) {
    return __builtin_amdgcn_rcpf(1.0f + __expf(-x));
}
__device__ __forceinline__ float tanh_fast(float x) {
    return 1.0f - 2.0f * __builtin_amdgcn_rcpf(__expf(2.0f * x) + 1.0f);
}

#define LINE(kt, lane) (((kt) * 64 + (lane)) * 16)
#define BUFBYTES (9 * 64 * 16)   /* 9216 B per buffer */

__global__ __launch_bounds__(512, 2) void rowlstm_mfma4(
    const float* __restrict__ x,   const float* __restrict__ Wis,
    const float* __restrict__ bis, const float* __restrict__ Wss,
    const float* __restrict__ bss, const float* __restrict__ h0,
    const float* __restrict__ c0,  float* __restrict__ out,
    u32* flags, char* halo)
{
    __shared__ __align__(16) char lds_buf[2 * BUFBYTES];   // 18432 B
    __shared__ u16  lds_x[3 * 64 * 17];                    // 6528 B
    __shared__ float lds_bias[512];                        // 2048 B

    const int tid  = threadIdx.x;
    const int s    = blockIdx.x;            // w-quarter
    const int b    = blockIdx.y;            // batch
    const int wid  = tid >> 6;              // wave [0,8) = hc-tile
    const int lane = tid & 63;
    const int q    = lane >> 4;             // quad
    const int n    = lane & 15;             // w within quarter
    const int wbase = s * 16;

    u32* flg_my = flags + ((size_t)b * 4 + s) * 8;
    u32* flg_up = flags + ((size_t)b * 4 + (s > 0 ? s - 1 : 0)) * 8;
    char* hs_my = halo + (((size_t)b * 4 + s) * 64) * 256;
    char* hs_up = halo + (((size_t)b * 4 + (s > 0 ? s - 1 : 0)) * 64) * 256;

    // ---------- phase 0: zero both B buffers ----------
    for (int i = tid; i < 1152; i += 512)
        *(uint4*)(lds_buf + i * 16) = make_uint4(0, 0, 0, 0);
    __syncthreads();

    // ---------- phase 1: one-time staging ----------
    lds_bias[tid] = bis[tid] + bss[tid];

    // x -> LDS bf16: [cch][r][wl1], wl1 = local w + 1 (col 0 = left halo col)
    for (int i = tid; i < 3264; i += 512) {
        int cch = i / 1088, rem = i % 1088;
        int r = rem / 17, wl1 = rem % 17;
        int gw = wbase + wl1 - 1;
        lds_x[i] = (gw < 0) ? (u16)0
                 : f2b(x[(((size_t)b * 3 + cch) * 64 + r) * 64 + gw]);
    }

    // A-fragments (persist in regs): a[j]=tap1(ic=kt*16+q*4+j), a[4+j]=tap0
    bf16x8 afr[4][9];
    {
        #pragma unroll
        for (int g = 0; g < 4; ++g) {
            int oc = g * 128 + wid * 16 + n;           // m = n
            #pragma unroll
            for (int kt = 0; kt < 8; ++kt) {
                bf16x8 a;
                #pragma unroll
                for (int jj = 0; jj < 4; ++jj) {
                    int ic = kt * 16 + q * 4 + jj;
                    float2 wp = *(const float2*)&Wss[(size_t)(oc * 128 + ic) * 3];
                    a[jj]     = (short)f2b(wp.y);      // tap1 (center)
                    a[4 + jj] = (short)f2b(wp.x);      // tap0 (left)
                }
                afr[g][kt] = a;
            }
            bf16x8 ax = {0, 0, 0, 0, 0, 0, 0, 0};
            if (q == 0) {
                #pragma unroll
                for (int cch = 0; cch < 3; ++cch) {
                    float2 wp = *(const float2*)&Wis[(size_t)(oc * 3 + cch) * 3];
                    ax[cch]     = (short)f2b(wp.y);
                    ax[4 + cch] = (short)f2b(wp.x);
                }
            }
            afr[g][8] = ax;
        }
    }

    // c-state (fp32, registers) + h0 publish into buf0
    float cst[4];
    {
        u16 hw[4];
        #pragma unroll
        for (int reg = 0; reg < 4; ++reg) {
            int hc = wid * 16 + q * 4 + reg;
            int wg = wbase + n;
            cst[reg] = c0[hc * 64 + wg];
            hw[reg] = f2b(h0[hc * 64 + wg]);
        }
        u64 d01 = (u64)((u32)hw[0] | ((u32)hw[1] << 16))
                | ((u64)((u32)hw[2] | ((u32)hw[3] << 16)) << 32);
        *(u64*)(lds_buf + LINE(wid, lane)) = d01;               // tap1 halves
        int wl = n + 1;
        if (wl < 16)
            *(u64*)(lds_buf + LINE(wid, q * 16 + wl) + 8) = d01;
    }
    // s>0: left-edge tap0 column from h0[:, wbase-1] (h0 is known globally)
    if (s > 0 && tid < 32) {
        int ic0 = tid * 4;
        u64 v = (u64)((u32)f2b(h0[(ic0 + 0) * 64 + wbase - 1]) | ((u32)f2b(h0[(ic0 + 1) * 64 + wbase - 1]) << 16))
              | ((u64)((u32)f2b(h0[(ic0 + 2) * 64 + wbase - 1]) | ((u32)f2b(h0[(ic0 + 3) * 64 + wbase - 1]) << 16)) << 32);
        *(u64*)(lds_buf + LINE(tid >> 2, (tid & 3) * 16) + 8) = v;
    }
    // x K-tile for row 0 into buf0 (q==0 lanes only; q>0 lanes stay zero)
    if (tid < 16) {
        int nn = tid;
        u32 d0 = (u32)lds_x[0 * 1088 + 0 * 17 + nn + 1] | ((u32)lds_x[1 * 1088 + 0 * 17 + nn + 1] << 16);
        u32 d1 = (u32)lds_x[2 * 1088 + 0 * 17 + nn + 1];
        u32 d2 = (u32)lds_x[0 * 1088 + 0 * 17 + nn]     | ((u32)lds_x[1 * 1088 + 0 * 17 + nn] << 16);
        u32 d3 = (u32)lds_x[2 * 1088 + 0 * 17 + nn];
        *(uint4*)(lds_buf + LINE(8, nn)) = make_uint4(d0, d1, d2, d3);
    }
    __syncthreads();

    // ================= row loop: ONE barrier per row =================
    for (int r = 0; r < 64; ++r) {
        char* rbuf = lds_buf + (r & 1) * BUFBYTES;
        char* wbuf = lds_buf + ((r & 1) ^ 1) * BUFBYTES;

        f32x4 acc[4];
        #pragma unroll
        for (int g = 0; g < 4; ++g) {
            int oc = g * 128 + wid * 16 + q * 4;
            acc[g][0] = lds_bias[oc + 0];
            acc[g][1] = lds_bias[oc + 1];
            acc[g][2] = lds_bias[oc + 2];
            acc[g][3] = lds_bias[oc + 3];
        }
        #pragma unroll
        for (int kt = 0; kt < 9; ++kt) {
            bf16x8 bv = *(const bf16x8*)(rbuf + LINE(kt, lane));
            acc[0] = __builtin_amdgcn_mfma_f32_16x16x32_bf16(afr[0][kt], bv, acc[0], 0, 0, 0);
            acc[1] = __builtin_amdgcn_mfma_f32_16x16x32_bf16(afr[1][kt], bv, acc[1], 0, 0, 0);
            acc[2] = __builtin_amdgcn_mfma_f32_16x16x32_bf16(afr[2][kt], bv, acc[2], 0, 0, 0);
            acc[3] = __builtin_amdgcn_mfma_f32_16x16x32_bf16(afr[3][kt], bv, acc[3], 0, 0, 0);
        }
        // D: col = n (w), row = q*4+reg (oc within tile)
        u16 hw[4];
        #pragma unroll
        for (int reg = 0; reg < 4; ++reg) {
            float o  = sigm(acc[0][reg]);
            float f  = sigm(acc[1][reg]);
            float ii = sigm(acc[2][reg]);
            float gg = sigm(acc[3][reg]);
            float cn = f * cst[reg] + ii * gg;
            cst[reg] = cn;
            float h = o * tanh_fast(cn);
            int hc = wid * 16 + q * 4 + reg;
            out[(((size_t)(b * 128 + hc)) * 64 + r) * 64 + wbase + n] = h;
            hw[reg] = f2b(h);
        }
        u64 d01 = (u64)((u32)hw[0] | ((u32)hw[1] << 16))
                | ((u64)((u32)hw[2] | ((u32)hw[3] << 16)) << 32);
        *(u64*)(wbuf + LINE(wid, lane)) = d01;                 // tap1 halves
        int wl = n + 1;
        if (wl < 16)
            *(u64*)(wbuf + LINE(wid, q * 16 + wl) + 8) = d01;
        else if (s < 3 && r < 63)                              // right edge -> s+1
            __hip_atomic_store((u64*)(hs_my + (size_t)r * 256 + (wid * 4 + q) * 8),
                               d01, __ATOMIC_RELAXED, __HIP_MEMORY_SCOPE_AGENT);

        // publish flag: this wave's halo store drained (per-wave vmcnt)
        if (s < 3 && lane == 15 && r < 63) {
            asm volatile("s_waitcnt vmcnt(0)" ::: "memory");
            __hip_atomic_store(&flg_my[wid], (u32)(r + 1),
                               __ATOMIC_RELAXED, __HIP_MEMORY_SCOPE_AGENT);
        }
        if (r < 63) {
            // x K-tile for row r+1
            if (tid < 16) {
                int nn = tid, r1 = r + 1;
                u32 d0 = (u32)lds_x[0 * 1088 + r1 * 17 + nn + 1] | ((u32)lds_x[1 * 1088 + r1 * 17 + nn + 1] << 16);
                u32 d1 = (u32)lds_x[2 * 1088 + r1 * 17 + nn + 1];
                u32 d2 = (u32)lds_x[0 * 1088 + r1 * 17 + nn]     | ((u32)lds_x[1 * 1088 + r1 * 17 + nn] << 16);
                u32 d3 = (u32)lds_x[2 * 1088 + r1 * 17 + nn];
                *(uint4*)(wbuf + LINE(8, nn)) = make_uint4(d0, d1, d2, d3);
            }
            // s>0: receive halo h[:, wbase-1] of row r -> left-edge tap0 column
            if (s > 0 && tid < 32) {
                while (__hip_atomic_load(&flg_up[tid >> 2], __ATOMIC_RELAXED,
                                         __HIP_MEMORY_SCOPE_AGENT) <= (u32)r)
                    __builtin_amdgcn_s_sleep(2);
                u64 v = __hip_atomic_load((u64*)(hs_up + (size_t)r * 256 + tid * 8),
                                          __ATOMIC_RELAXED, __HIP_MEMORY_SCOPE_AGENT);
                *(u64*)(wbuf + LINE(tid >> 2, (tid & 3) * 16) + 8) = v;
            }
        }
        __syncthreads();
    }
}

extern "C" void kernel_launch(void* const* d_in, const int* in_sizes, int n_in,
                              void* d_out, int out_size, void* d_ws, size_t ws_size,
                              hipStream_t stream)
{
    const float* x   = (const float*)d_in[0];
    const float* Wis = (const float*)d_in[1];
    const float* bis = (const float*)d_in[2];
    const float* Wss = (const float*)d_in[3];
    const float* bss = (const float*)d_in[4];
    const float* h0  = (const float*)d_in[5];
    const float* c0  = (const float*)d_in[6];
    float* out = (float*)d_out;

    // flags: 32 b x 4 s x 8 wid u32 (4096 B); halo slots at +4096: 32*4*64*256 = 2 MB
    hipMemsetAsync(d_ws, 0, 4096, stream);
    rowlstm_mfma4<<<dim3(4, 32), 512, 0, stream>>>(
        x, Wis, bis, Wss, bss, h0, c0, out,
        (u32*)d_ws, (char*)d_ws + 4096);
}